// Round 1
// baseline (495.913 us; speedup 1.0000x reference)
//
#include <hip/hip_runtime.h>
#include <hip/hip_bf16.h>

#define NUMH 16
#define HD   64
#define EMB  1024
#define SEQL 2048
#define BATCH 4

typedef __attribute__((ext_vector_type(8))) short bf16x8;
typedef __attribute__((ext_vector_type(4))) float f32x4;

__device__ __forceinline__ unsigned short f2bf(float f) {
  union { float f; unsigned int u; } v; v.f = f;
  unsigned int u = v.u + 0x7fffu + ((v.u >> 16) & 1u);
  return (unsigned short)(u >> 16);
}

// ---------------- QKV projection: [8192,1024] x [1024,3072] + bias ----------
// writes Q,K,V as bf16 in [B][H][S][64]
__global__ __launch_bounds__(256, 2) void gemm_qkv(
    const float* __restrict__ X, const float* __restrict__ W,
    const float* __restrict__ Bias,
    unsigned short* __restrict__ Qo, unsigned short* __restrict__ Ko,
    unsigned short* __restrict__ Vo) {
  __shared__ __align__(16) unsigned short As[128][40];
  __shared__ __align__(16) unsigned short Bs[128][40]; // B^T: [n][k]
  const int tid  = threadIdx.x;
  const int lane = tid & 63;
  const int wv   = tid >> 6;
  const int wrow = (wv >> 1) * 64, wcol = (wv & 1) * 64;
  const int l15  = lane & 15, lg = lane >> 4;
  const int mbase = blockIdx.y * 128, nbase = blockIdx.x * 128;

  f32x4 acc[4][4];
#pragma unroll
  for (int i = 0; i < 4; ++i)
#pragma unroll
    for (int j = 0; j < 4; ++j) acc[i][j] = (f32x4){0.f, 0.f, 0.f, 0.f};

  const int arow = tid >> 1, akb = (tid & 1) * 16;
  const int bk = tid >> 3, bn0 = tid & 7;
  const float* aptr = X + (size_t)(mbase + arow) * EMB + akb;
  const float* bptr = W + (size_t)bk * 3072 + nbase + bn0;

  for (int k0 = 0; k0 < EMB; k0 += 32) {
    __syncthreads();
    // ---- stage A (fp32 -> bf16), 16 elems/thread, k-contiguous ----
    float4 a0 = *(const float4*)(aptr + k0);
    float4 a1 = *(const float4*)(aptr + k0 + 4);
    float4 a2 = *(const float4*)(aptr + k0 + 8);
    float4 a3 = *(const float4*)(aptr + k0 + 12);
    bf16x8 w0, w1;
    w0[0]=(short)f2bf(a0.x); w0[1]=(short)f2bf(a0.y); w0[2]=(short)f2bf(a0.z); w0[3]=(short)f2bf(a0.w);
    w0[4]=(short)f2bf(a1.x); w0[5]=(short)f2bf(a1.y); w0[6]=(short)f2bf(a1.z); w0[7]=(short)f2bf(a1.w);
    w1[0]=(short)f2bf(a2.x); w1[1]=(short)f2bf(a2.y); w1[2]=(short)f2bf(a2.z); w1[3]=(short)f2bf(a2.w);
    w1[4]=(short)f2bf(a3.x); w1[5]=(short)f2bf(a3.y); w1[6]=(short)f2bf(a3.z); w1[7]=(short)f2bf(a3.w);
    *(bf16x8*)&As[arow][akb]     = w0;
    *(bf16x8*)&As[arow][akb + 8] = w1;
    // ---- stage B^T (fp32 -> bf16), stride-8 n per thread (bank-spread) ----
    const float* bp = bptr + (size_t)k0 * 3072;
#pragma unroll
    for (int i = 0; i < 16; ++i)
      Bs[bn0 + 8 * i][bk] = f2bf(bp[8 * i]);
    __syncthreads();
    // ---- MFMA ----
    bf16x8 af[4], bfr[4];
#pragma unroll
    for (int mf = 0; mf < 4; ++mf)
      af[mf] = *(const bf16x8*)&As[wrow + mf * 16 + l15][lg * 8];
#pragma unroll
    for (int nf = 0; nf < 4; ++nf)
      bfr[nf] = *(const bf16x8*)&Bs[wcol + nf * 16 + l15][lg * 8];
#pragma unroll
    for (int mf = 0; mf < 4; ++mf)
#pragma unroll
      for (int nf = 0; nf < 4; ++nf)
        acc[mf][nf] = __builtin_amdgcn_mfma_f32_16x16x32_bf16(af[mf], bfr[nf], acc[mf][nf], 0, 0, 0);
  }

  // epilogue: scatter into Q/K/V [B][H][S][64] bf16
#pragma unroll
  for (int nf = 0; nf < 4; ++nf) {
    const int n = nbase + wcol + nf * 16 + l15;
    const float bias = Bias[n];
    const int which = n >> 10;
    const int rem = n & 1023;
    const int h = rem >> 6, d = rem & 63;
    unsigned short* dst = (which == 0) ? Qo : (which == 1) ? Ko : Vo;
#pragma unroll
    for (int mf = 0; mf < 4; ++mf) {
#pragma unroll
      for (int j = 0; j < 4; ++j) {
        const int m = mbase + wrow + mf * 16 + lg * 4 + j;
        const int bb = m >> 11, s = m & 2047;
        dst[((size_t)(bb * NUMH + h) * SEQL + s) * HD + d] = f2bf(acc[mf][nf][j] + bias);
      }
    }
  }
}

// ---------------- causal flash attention, bf16 in/out ----------------------
// block = 128 q rows of one (b,h); 4 waves x 32 rows; KV tile = 128
__global__ __launch_bounds__(256, 2) void attn_fwd(
    const unsigned short* __restrict__ Q, const unsigned short* __restrict__ K,
    const unsigned short* __restrict__ V, unsigned short* __restrict__ O) {
  __shared__ __align__(16) unsigned short VT[64][136];     // V^T [d][kv]
  __shared__ __align__(16) unsigned short P[4][32][136];   // per-wave P
  const int tid = threadIdx.x;
  const int lane = tid & 63;
  const int wv = tid >> 6;
  const int l15 = lane & 15, lg = lane >> 4;
  const int qt = blockIdx.x, h = blockIdx.y, b = blockIdx.z;
  const size_t bh = (size_t)(b * NUMH + h) * SEQL * HD;
  const unsigned short* Qb = Q + bh;
  const unsigned short* Kb = K + bh;
  const unsigned short* Vb = V + bh;
  const int qrow0 = qt * 128 + wv * 32;

  // Q fragments in registers: rows qrow0..+31, K(=d) 64 split into 2 MFMA steps
  bf16x8 qf[2][2];
#pragma unroll
  for (int mf = 0; mf < 2; ++mf)
#pragma unroll
    for (int ks = 0; ks < 2; ++ks)
      qf[mf][ks] = *(const bf16x8*)&Qb[(size_t)(qrow0 + mf * 16 + l15) * HD + ks * 32 + lg * 8];

  f32x4 o[2][4];
  float mrun[2][4], lrun[2][4];
#pragma unroll
  for (int mf = 0; mf < 2; ++mf)
#pragma unroll
    for (int j = 0; j < 4; ++j) {
      mrun[mf][j] = -1e30f; lrun[mf][j] = 0.f;
      if (j == 0) { o[mf][0] = (f32x4){0,0,0,0}; o[mf][1] = (f32x4){0,0,0,0};
                    o[mf][2] = (f32x4){0,0,0,0}; o[mf][3] = (f32x4){0,0,0,0}; }
    }

  for (int kt = 0; kt <= qt; ++kt) {
    __syncthreads();  // prior PV done reading VT
    { // stage V^T: 128 rows x 64 d, 2 threads/row
      const int vrow = tid >> 1, vd = (tid & 1) * 32;
      const uint4* vp = (const uint4*)&Vb[(size_t)(kt * 128 + vrow) * HD + vd];
      union { uint4 q[4]; unsigned short s[32]; } vbuf;
      vbuf.q[0] = vp[0]; vbuf.q[1] = vp[1]; vbuf.q[2] = vp[2]; vbuf.q[3] = vp[3];
#pragma unroll
      for (int i = 0; i < 32; ++i) VT[vd + i][vrow] = vbuf.s[i];
    }
    __syncthreads();

    // ---- S = Q K^T (K frags straight from global; L2-resident) ----
    f32x4 s[2][8];
#pragma unroll
    for (int mf = 0; mf < 2; ++mf)
#pragma unroll
      for (int nf = 0; nf < 8; ++nf) s[mf][nf] = (f32x4){0.f, 0.f, 0.f, 0.f};
#pragma unroll
    for (int ks = 0; ks < 2; ++ks) {
#pragma unroll
      for (int nf = 0; nf < 8; ++nf) {
        bf16x8 kf = *(const bf16x8*)&Kb[(size_t)(kt * 128 + nf * 16 + l15) * HD + ks * 32 + lg * 8];
        s[0][nf] = __builtin_amdgcn_mfma_f32_16x16x32_bf16(qf[0][ks], kf, s[0][nf], 0, 0, 0);
        s[1][nf] = __builtin_amdgcn_mfma_f32_16x16x32_bf16(qf[1][ks], kf, s[1][nf], 0, 0, 0);
      }
    }
    // ---- scale + causal mask ----
    const bool diag = (kt == qt);
#pragma unroll
    for (int mf = 0; mf < 2; ++mf)
#pragma unroll
      for (int j = 0; j < 4; ++j) {
        const int qr = qrow0 + mf * 16 + lg * 4 + j;
#pragma unroll
        for (int nf = 0; nf < 8; ++nf) {
          float v = s[mf][nf][j] * 0.125f;
          const int kc = kt * 128 + nf * 16 + l15;
          if (diag && kc > qr) v = -1e30f;
          s[mf][nf][j] = v;
        }
      }
    // ---- online softmax per row (row lives in one 16-lane group) ----
#pragma unroll
    for (int mf = 0; mf < 2; ++mf) {
#pragma unroll
      for (int j = 0; j < 4; ++j) {
        float pm = s[mf][0][j];
#pragma unroll
        for (int nf = 1; nf < 8; ++nf) pm = fmaxf(pm, s[mf][nf][j]);
        pm = fmaxf(pm, __shfl_xor(pm, 1));
        pm = fmaxf(pm, __shfl_xor(pm, 2));
        pm = fmaxf(pm, __shfl_xor(pm, 4));
        pm = fmaxf(pm, __shfl_xor(pm, 8));
        const float mn = fmaxf(mrun[mf][j], pm);
        const float sc = __expf(mrun[mf][j] - mn);
        mrun[mf][j] = mn;
        float rs = 0.f;
        const int prow = mf * 16 + lg * 4 + j;
#pragma unroll
        for (int nf = 0; nf < 8; ++nf) {
          const float p = __expf(s[mf][nf][j] - mn);
          rs += p;
          P[wv][prow][nf * 16 + l15] = f2bf(p);
        }
        rs += __shfl_xor(rs, 1);
        rs += __shfl_xor(rs, 2);
        rs += __shfl_xor(rs, 4);
        rs += __shfl_xor(rs, 8);
        lrun[mf][j] = lrun[mf][j] * sc + rs;
#pragma unroll
        for (int df = 0; df < 4; ++df) o[mf][df][j] *= sc;
      }
    }
    // ---- O += P V (P from LDS as A-frags; VT as B-frags) ----
#pragma unroll
    for (int ks = 0; ks < 4; ++ks) {
      bf16x8 pa0 = *(const bf16x8*)&P[wv][l15][ks * 32 + lg * 8];
      bf16x8 pa1 = *(const bf16x8*)&P[wv][16 + l15][ks * 32 + lg * 8];
#pragma unroll
      for (int df = 0; df < 4; ++df) {
        bf16x8 vf = *(const bf16x8*)&VT[df * 16 + l15][ks * 32 + lg * 8];
        o[0][df] = __builtin_amdgcn_mfma_f32_16x16x32_bf16(pa0, vf, o[0][df], 0, 0, 0);
        o[1][df] = __builtin_amdgcn_mfma_f32_16x16x32_bf16(pa1, vf, o[1][df], 0, 0, 0);
      }
    }
  }
  // ---- epilogue: attn_out bf16 [B][S][H*64] ----
  unsigned short* Ob = O + (size_t)b * SEQL * EMB + h * HD;
#pragma unroll
  for (int mf = 0; mf < 2; ++mf)
#pragma unroll
    for (int j = 0; j < 4; ++j) {
      const float inv = 1.f / lrun[mf][j];
      const int srow = qrow0 + mf * 16 + lg * 4 + j;
#pragma unroll
      for (int df = 0; df < 4; ++df)
        Ob[(size_t)srow * EMB + df * 16 + l15] = f2bf(o[mf][df][j] * inv);
    }
}

// ---------------- out projection: [8192,1024](bf16) x [1024,1024] + bias ---
__global__ __launch_bounds__(256, 2) void gemm_out(
    const unsigned short* __restrict__ Ain, const float* __restrict__ W,
    const float* __restrict__ Bias, float* __restrict__ Out) {
  __shared__ __align__(16) unsigned short As[128][40];
  __shared__ __align__(16) unsigned short Bs[128][40];
  const int tid = threadIdx.x;
  const int lane = tid & 63;
  const int wv = tid >> 6;
  const int wrow = (wv >> 1) * 64, wcol = (wv & 1) * 64;
  const int l15 = lane & 15, lg = lane >> 4;
  const int mbase = blockIdx.y * 128, nbase = blockIdx.x * 128;

  f32x4 acc[4][4];
#pragma unroll
  for (int i = 0; i < 4; ++i)
#pragma unroll
    for (int j = 0; j < 4; ++j) acc[i][j] = (f32x4){0.f, 0.f, 0.f, 0.f};

  const int arow = tid >> 1, akb = (tid & 1) * 16;
  const int bk = tid >> 3, bn0 = tid & 7;
  const unsigned short* aptr = Ain + (size_t)(mbase + arow) * EMB + akb;
  const float* bptr = W + (size_t)bk * EMB + nbase + bn0;

  for (int k0 = 0; k0 < EMB; k0 += 32) {
    __syncthreads();
    *(bf16x8*)&As[arow][akb]     = *(const bf16x8*)(aptr + k0);
    *(bf16x8*)&As[arow][akb + 8] = *(const bf16x8*)(aptr + k0 + 8);
    const float* bp = bptr + (size_t)k0 * EMB;
#pragma unroll
    for (int i = 0; i < 16; ++i)
      Bs[bn0 + 8 * i][bk] = f2bf(bp[8 * i]);
    __syncthreads();
    bf16x8 af[4], bfr[4];
#pragma unroll
    for (int mf = 0; mf < 4; ++mf)
      af[mf] = *(const bf16x8*)&As[wrow + mf * 16 + l15][lg * 8];
#pragma unroll
    for (int nf = 0; nf < 4; ++nf)
      bfr[nf] = *(const bf16x8*)&Bs[wcol + nf * 16 + l15][lg * 8];
#pragma unroll
    for (int mf = 0; mf < 4; ++mf)
#pragma unroll
      for (int nf = 0; nf < 4; ++nf)
        acc[mf][nf] = __builtin_amdgcn_mfma_f32_16x16x32_bf16(af[mf], bfr[nf], acc[mf][nf], 0, 0, 0);
  }

#pragma unroll
  for (int nf = 0; nf < 4; ++nf) {
    const int n = nbase + wcol + nf * 16 + l15;
    const float bias = Bias[n];
#pragma unroll
    for (int mf = 0; mf < 4; ++mf) {
#pragma unroll
      for (int j = 0; j < 4; ++j) {
        const int m = mbase + wrow + mf * 16 + lg * 4 + j;
        Out[(size_t)m * EMB + n] = acc[mf][nf][j] + bias;
      }
    }
  }
}

extern "C" void kernel_launch(void* const* d_in, const int* in_sizes, int n_in,
                              void* d_out, int out_size, void* d_ws, size_t ws_size,
                              hipStream_t stream) {
  const float* x     = (const float*)d_in[0];
  const float* w_qkv = (const float*)d_in[1];
  const float* b_qkv = (const float*)d_in[2];
  const float* w_out = (const float*)d_in[3];
  const float* b_out = (const float*)d_in[4];
  float* out = (float*)d_out;

  const size_t NE = (size_t)BATCH * NUMH * SEQL * HD;  // 8,388,608 per tensor
  unsigned short* Qb = (unsigned short*)d_ws;
  unsigned short* Kb = Qb + NE;
  unsigned short* Vb = Kb + NE;
  unsigned short* AO = Vb + NE;  // attn out, bf16 [B][S][1024]

  gemm_qkv<<<dim3(3072 / 128, 8192 / 128), 256, 0, stream>>>(x, w_qkv, b_qkv, Qb, Kb, Vb);
  attn_fwd<<<dim3(SEQL / 128, NUMH, BATCH), 256, 0, stream>>>(Qb, Kb, Vb, AO);
  gemm_out<<<dim3(EMB / 128, 8192 / 128), 256, 0, stream>>>(AO, w_out, b_out, out);
}

// Round 2
// 361.992 us; speedup vs baseline: 1.3700x; 1.3700x over previous
//
#include <hip/hip_runtime.h>
#include <hip/hip_bf16.h>

#define NUMH 16
#define HD   64
#define EMB  1024
#define SEQL 2048
#define BATCH 4

typedef __attribute__((ext_vector_type(8))) short bf16x8;
typedef __attribute__((ext_vector_type(4))) float f32x4;

__device__ __forceinline__ unsigned short f2bf(float f) {
  union { float f; unsigned int u; } v; v.f = f;
  unsigned int u = v.u + 0x7fffu + ((v.u >> 16) & 1u);
  return (unsigned short)(u >> 16);
}

#define GLOAD16(gp, lp)                                                        \
  __builtin_amdgcn_global_load_lds(                                            \
      (const __attribute__((address_space(1))) unsigned int*)(gp),             \
      (__attribute__((address_space(3))) unsigned int*)(lp), 16, 0, 0)

// ---------- convert x fp32 -> bf16 (8M elems) ----------
__global__ __launch_bounds__(256) void cvt_x(const float* __restrict__ src,
                                             unsigned short* __restrict__ dst) {
  const size_t i = ((size_t)blockIdx.x * 256 + threadIdx.x) * 8;
  float4 a = *(const float4*)(src + i);
  float4 b = *(const float4*)(src + i + 4);
  bf16x8 w;
  w[0]=(short)f2bf(a.x); w[1]=(short)f2bf(a.y); w[2]=(short)f2bf(a.z); w[3]=(short)f2bf(a.w);
  w[4]=(short)f2bf(b.x); w[5]=(short)f2bf(b.y); w[6]=(short)f2bf(b.z); w[7]=(short)f2bf(b.w);
  *(bf16x8*)(dst + i) = w;
}

// ---------- transpose + convert: src[R][C] fp32 -> dst[C][R] bf16 ----------
__global__ __launch_bounds__(256) void tr_cvt(const float* __restrict__ src,
                                              unsigned short* __restrict__ dst,
                                              int R, int C) {
  __shared__ unsigned short t[32][34];
  const int tx = threadIdx.x & 31, ty = threadIdx.x >> 5;
  const int c0 = blockIdx.x * 32, r0 = blockIdx.y * 32;
#pragma unroll
  for (int i = 0; i < 4; ++i)
    t[ty + i * 8][tx] = f2bf(src[(size_t)(r0 + ty + i * 8) * C + c0 + tx]);
  __syncthreads();
#pragma unroll
  for (int i = 0; i < 4; ++i)
    dst[(size_t)(c0 + ty + i * 8) * R + r0 + tx] = t[tx][ty + i * 8];
}

// ---------- m97-style GEMM: A[M][1024] bf16, BT[N][1024] bf16 ----------
// 128x128 tile, BK=32, global_load_lds width 16, 4 waves 2x2, acc 4x4.
__global__ __launch_bounds__(256, 3) void gemm_qkv(
    const unsigned short* __restrict__ A, const unsigned short* __restrict__ BT,
    const float* __restrict__ Bias,
    unsigned short* __restrict__ Qo, unsigned short* __restrict__ Ko,
    unsigned short* __restrict__ Vo) {
  __shared__ __align__(16) unsigned short As[128][32];
  __shared__ __align__(16) unsigned short Bs[128][32];
  const int tid = threadIdx.x, lane = tid & 63, wv = tid >> 6;
  const int l15 = lane & 15, lg = lane >> 4;
  const int wrow = (wv >> 1) * 64, wcol = (wv & 1) * 64;
  // bijective XCD swizzle (nwg = 1536, %8==0)
  const int cpx = gridDim.x >> 3;
  const int wg = (blockIdx.x & 7) * cpx + (blockIdx.x >> 3);
  const int mbase = (wg / 24) * 128, nbase = (wg % 24) * 128;

  f32x4 acc[4][4];
#pragma unroll
  for (int i = 0; i < 4; ++i)
#pragma unroll
    for (int j = 0; j < 4; ++j) acc[i][j] = (f32x4){0.f, 0.f, 0.f, 0.f};

  const int c0 = wv * 64 + lane;  // staging chunk 0..255 (row=c>>2, kc=c&3)
  const unsigned short* ga0 = A + (size_t)(mbase + (c0 >> 2)) * EMB + (c0 & 3) * 8;
  const unsigned short* ga1 = ga0 + (size_t)64 * EMB;
  const unsigned short* gb0 = BT + (size_t)(nbase + (c0 >> 2)) * EMB + (c0 & 3) * 8;
  const unsigned short* gb1 = gb0 + (size_t)64 * EMB;
  unsigned short* la0 = &As[0][0] + c0 * 8;
  unsigned short* lb0 = &Bs[0][0] + c0 * 8;

  for (int k0 = 0; k0 < EMB; k0 += 32) {
    __syncthreads();
    GLOAD16(ga0 + k0, la0);
    GLOAD16(ga1 + k0, la0 + 2048);
    GLOAD16(gb0 + k0, lb0);
    GLOAD16(gb1 + k0, lb0 + 2048);
    __syncthreads();
    bf16x8 af[4], bfr[4];
#pragma unroll
    for (int mf = 0; mf < 4; ++mf)
      af[mf] = *(const bf16x8*)&As[wrow + mf * 16 + l15][lg * 8];
#pragma unroll
    for (int nf = 0; nf < 4; ++nf)
      bfr[nf] = *(const bf16x8*)&Bs[wcol + nf * 16 + l15][lg * 8];
#pragma unroll
    for (int mf = 0; mf < 4; ++mf)
#pragma unroll
      for (int nf = 0; nf < 4; ++nf)
        acc[mf][nf] = __builtin_amdgcn_mfma_f32_16x16x32_bf16(af[mf], bfr[nf], acc[mf][nf], 0, 0, 0);
  }

#pragma unroll
  for (int nf = 0; nf < 4; ++nf) {
    const int n = nbase + wcol + nf * 16 + l15;
    const float bias = Bias[n];
    const int which = n >> 10, rem = n & 1023;
    const int h = rem >> 6, d = rem & 63;
    unsigned short* dst = (which == 0) ? Qo : (which == 1) ? Ko : Vo;
#pragma unroll
    for (int mf = 0; mf < 4; ++mf)
#pragma unroll
      for (int j = 0; j < 4; ++j) {
        const int m = mbase + wrow + mf * 16 + lg * 4 + j;
        const int bb = m >> 11, s = m & 2047;
        dst[((size_t)(bb * NUMH + h) * SEQL + s) * HD + d] = f2bf(acc[mf][nf][j] + bias);
      }
  }
}

__global__ __launch_bounds__(256, 3) void gemm_out(
    const unsigned short* __restrict__ A, const unsigned short* __restrict__ BT,
    const float* __restrict__ Bias, float* __restrict__ Out) {
  __shared__ __align__(16) unsigned short As[128][32];
  __shared__ __align__(16) unsigned short Bs[128][32];
  const int tid = threadIdx.x, lane = tid & 63, wv = tid >> 6;
  const int l15 = lane & 15, lg = lane >> 4;
  const int wrow = (wv >> 1) * 64, wcol = (wv & 1) * 64;
  const int cpx = gridDim.x >> 3;  // nwg = 512
  const int wg = (blockIdx.x & 7) * cpx + (blockIdx.x >> 3);
  const int mbase = (wg >> 3) * 128, nbase = (wg & 7) * 128;

  f32x4 acc[4][4];
#pragma unroll
  for (int i = 0; i < 4; ++i)
#pragma unroll
    for (int j = 0; j < 4; ++j) acc[i][j] = (f32x4){0.f, 0.f, 0.f, 0.f};

  const int c0 = wv * 64 + lane;
  const unsigned short* ga0 = A + (size_t)(mbase + (c0 >> 2)) * EMB + (c0 & 3) * 8;
  const unsigned short* ga1 = ga0 + (size_t)64 * EMB;
  const unsigned short* gb0 = BT + (size_t)(nbase + (c0 >> 2)) * EMB + (c0 & 3) * 8;
  const unsigned short* gb1 = gb0 + (size_t)64 * EMB;
  unsigned short* la0 = &As[0][0] + c0 * 8;
  unsigned short* lb0 = &Bs[0][0] + c0 * 8;

  for (int k0 = 0; k0 < EMB; k0 += 32) {
    __syncthreads();
    GLOAD16(ga0 + k0, la0);
    GLOAD16(ga1 + k0, la0 + 2048);
    GLOAD16(gb0 + k0, lb0);
    GLOAD16(gb1 + k0, lb0 + 2048);
    __syncthreads();
    bf16x8 af[4], bfr[4];
#pragma unroll
    for (int mf = 0; mf < 4; ++mf)
      af[mf] = *(const bf16x8*)&As[wrow + mf * 16 + l15][lg * 8];
#pragma unroll
    for (int nf = 0; nf < 4; ++nf)
      bfr[nf] = *(const bf16x8*)&Bs[wcol + nf * 16 + l15][lg * 8];
#pragma unroll
    for (int mf = 0; mf < 4; ++mf)
#pragma unroll
      for (int nf = 0; nf < 4; ++nf)
        acc[mf][nf] = __builtin_amdgcn_mfma_f32_16x16x32_bf16(af[mf], bfr[nf], acc[mf][nf], 0, 0, 0);
  }

#pragma unroll
  for (int nf = 0; nf < 4; ++nf) {
    const int n = nbase + wcol + nf * 16 + l15;
    const float bias = Bias[n];
#pragma unroll
    for (int mf = 0; mf < 4; ++mf)
#pragma unroll
      for (int j = 0; j < 4; ++j) {
        const int m = mbase + wrow + mf * 16 + lg * 4 + j;
        Out[(size_t)m * EMB + n] = acc[mf][nf][j] + bias;
      }
  }
}

// ---------------- causal flash attention, balanced pairs -------------------
// 512 blocks; block d: qp=(d>>3)&7, bh=((d&7)<<3)|(d>>6)  (same-bh -> same XCD)
// processes q-tiles qp and 15-qp => 17 kt-iters every block.
__global__ __launch_bounds__(256, 3) void attn_fwd(
    const unsigned short* __restrict__ Q, const unsigned short* __restrict__ K,
    const unsigned short* __restrict__ V, unsigned short* __restrict__ O) {
  __shared__ __align__(16) unsigned short VT[64][136];   // V^T [d][kv]
  __shared__ __align__(16) unsigned short P[4][32][136]; // per-wave P
  const int tid = threadIdx.x, lane = tid & 63, wv = tid >> 6;
  const int l15 = lane & 15, lg = lane >> 4;
  const int d0 = blockIdx.x;
  const int qp = (d0 >> 3) & 7;
  const int bh = ((d0 & 7) << 3) | (d0 >> 6);
  const int b = bh >> 4, h = bh & 15;
  const size_t bho = (size_t)(b * NUMH + h) * SEQL * HD;
  const unsigned short* Qb = Q + bho;
  const unsigned short* Kb = K + bho;
  const unsigned short* Vb = V + bho;
  unsigned short* Ob = O + (size_t)b * SEQL * EMB + h * HD;

  for (int pass = 0; pass < 2; ++pass) {
    const int qt = pass ? (15 - qp) : qp;
    const int qrow0 = qt * 128 + wv * 32;

    bf16x8 qf[2][2];
#pragma unroll
    for (int mf = 0; mf < 2; ++mf)
#pragma unroll
      for (int ks = 0; ks < 2; ++ks)
        qf[mf][ks] = *(const bf16x8*)&Qb[(size_t)(qrow0 + mf * 16 + l15) * HD + ks * 32 + lg * 8];

    f32x4 o[2][4];
    float mrun[2][4], lrun[2][4];
#pragma unroll
    for (int mf = 0; mf < 2; ++mf)
#pragma unroll
      for (int df = 0; df < 4; ++df) o[mf][df] = (f32x4){0.f, 0.f, 0.f, 0.f};
#pragma unroll
    for (int mf = 0; mf < 2; ++mf)
#pragma unroll
      for (int j = 0; j < 4; ++j) { mrun[mf][j] = -1e30f; lrun[mf][j] = 0.f; }

    for (int kt = 0; kt <= qt; ++kt) {
      __syncthreads();
      {  // stage V^T
        const int vrow = tid >> 1, vd = (tid & 1) * 32;
        const uint4* vp = (const uint4*)&Vb[(size_t)(kt * 128 + vrow) * HD + vd];
        union { uint4 q[4]; unsigned short s[32]; } vbuf;
        vbuf.q[0] = vp[0]; vbuf.q[1] = vp[1]; vbuf.q[2] = vp[2]; vbuf.q[3] = vp[3];
#pragma unroll
        for (int i = 0; i < 32; ++i) VT[vd + i][vrow] = vbuf.s[i];
      }
      __syncthreads();

      f32x4 s[2][8];
#pragma unroll
      for (int mf = 0; mf < 2; ++mf)
#pragma unroll
        for (int nf = 0; nf < 8; ++nf) s[mf][nf] = (f32x4){0.f, 0.f, 0.f, 0.f};
#pragma unroll
      for (int ks = 0; ks < 2; ++ks) {
#pragma unroll
        for (int nf = 0; nf < 8; ++nf) {
          bf16x8 kf = *(const bf16x8*)&Kb[(size_t)(kt * 128 + nf * 16 + l15) * HD + ks * 32 + lg * 8];
          s[0][nf] = __builtin_amdgcn_mfma_f32_16x16x32_bf16(qf[0][ks], kf, s[0][nf], 0, 0, 0);
          s[1][nf] = __builtin_amdgcn_mfma_f32_16x16x32_bf16(qf[1][ks], kf, s[1][nf], 0, 0, 0);
        }
      }
      const bool diag = (kt == qt);
#pragma unroll
      for (int mf = 0; mf < 2; ++mf)
#pragma unroll
        for (int j = 0; j < 4; ++j) {
          const int qr = qrow0 + mf * 16 + lg * 4 + j;
#pragma unroll
          for (int nf = 0; nf < 8; ++nf) {
            float vsc = s[mf][nf][j] * 0.125f;
            const int kc = kt * 128 + nf * 16 + l15;
            if (diag && kc > qr) vsc = -1e30f;
            s[mf][nf][j] = vsc;
          }
        }
#pragma unroll
      for (int mf = 0; mf < 2; ++mf) {
#pragma unroll
        for (int j = 0; j < 4; ++j) {
          float pm = s[mf][0][j];
#pragma unroll
          for (int nf = 1; nf < 8; ++nf) pm = fmaxf(pm, s[mf][nf][j]);
          pm = fmaxf(pm, __shfl_xor(pm, 1));
          pm = fmaxf(pm, __shfl_xor(pm, 2));
          pm = fmaxf(pm, __shfl_xor(pm, 4));
          pm = fmaxf(pm, __shfl_xor(pm, 8));
          const float mn = fmaxf(mrun[mf][j], pm);
          const float sc = __expf(mrun[mf][j] - mn);
          mrun[mf][j] = mn;
          float rs = 0.f;
          const int prow = mf * 16 + lg * 4 + j;
#pragma unroll
          for (int nf = 0; nf < 8; ++nf) {
            const float p = __expf(s[mf][nf][j] - mn);
            rs += p;
            P[wv][prow][nf * 16 + l15] = f2bf(p);
          }
          rs += __shfl_xor(rs, 1);
          rs += __shfl_xor(rs, 2);
          rs += __shfl_xor(rs, 4);
          rs += __shfl_xor(rs, 8);
          lrun[mf][j] = lrun[mf][j] * sc + rs;
#pragma unroll
          for (int df = 0; df < 4; ++df) o[mf][df][j] *= sc;
        }
      }
#pragma unroll
      for (int ks = 0; ks < 4; ++ks) {
        bf16x8 pa0 = *(const bf16x8*)&P[wv][l15][ks * 32 + lg * 8];
        bf16x8 pa1 = *(const bf16x8*)&P[wv][16 + l15][ks * 32 + lg * 8];
#pragma unroll
        for (int df = 0; df < 4; ++df) {
          bf16x8 vf = *(const bf16x8*)&VT[df * 16 + l15][ks * 32 + lg * 8];
          o[0][df] = __builtin_amdgcn_mfma_f32_16x16x32_bf16(pa0, vf, o[0][df], 0, 0, 0);
          o[1][df] = __builtin_amdgcn_mfma_f32_16x16x32_bf16(pa1, vf, o[1][df], 0, 0, 0);
        }
      }
    }
#pragma unroll
    for (int mf = 0; mf < 2; ++mf)
#pragma unroll
      for (int j = 0; j < 4; ++j) {
        const float inv = 1.f / lrun[mf][j];
        const int srow = qrow0 + mf * 16 + lg * 4 + j;
#pragma unroll
        for (int df = 0; df < 4; ++df)
          Ob[(size_t)srow * EMB + df * 16 + l15] = f2bf(o[mf][df][j] * inv);
      }
    __syncthreads();  // VT/P reuse across passes
  }
}

extern "C" void kernel_launch(void* const* d_in, const int* in_sizes, int n_in,
                              void* d_out, int out_size, void* d_ws, size_t ws_size,
                              hipStream_t stream) {
  const float* x     = (const float*)d_in[0];
  const float* w_qkv = (const float*)d_in[1];
  const float* b_qkv = (const float*)d_in[2];
  const float* w_out = (const float*)d_in[3];
  const float* b_out = (const float*)d_in[4];
  float* out = (float*)d_out;

  const size_t NE = (size_t)BATCH * NUMH * SEQL * HD;  // 8,388,608
  unsigned short* Qb = (unsigned short*)d_ws;
  unsigned short* Kb = Qb + NE;
  unsigned short* Vb = Kb + NE;
  unsigned short* AO = Vb + NE;
  unsigned short* xb = AO + NE;
  unsigned short* wqkvT = xb + NE;              // [3072][1024]
  unsigned short* woutT = wqkvT + 3072 * 1024;  // [1024][1024]

  cvt_x<<<dim3((unsigned)(NE / (256 * 8))), 256, 0, stream>>>(x, xb);
  tr_cvt<<<dim3(3072 / 32, 1024 / 32), 256, 0, stream>>>(w_qkv, wqkvT, 1024, 3072);
  tr_cvt<<<dim3(1024 / 32, 1024 / 32), 256, 0, stream>>>(w_out, woutT, 1024, 1024);

  gemm_qkv<<<dim3(1536), 256, 0, stream>>>(xb, wqkvT, b_qkv, Qb, Kb, Vb);
  attn_fwd<<<dim3(512), 256, 0, stream>>>(Qb, Kb, Vb, AO);
  gemm_out<<<dim3(512), 256, 0, stream>>>(AO, woutT, b_out, out);
}

// Round 3
// 273.912 us; speedup vs baseline: 1.8105x; 1.3216x over previous
//
#include <hip/hip_runtime.h>
#include <hip/hip_bf16.h>

#define NUMH 16
#define HD   64
#define EMB  1024
#define SEQL 2048
#define BATCH 4

typedef __attribute__((ext_vector_type(8))) short bf16x8;
typedef __attribute__((ext_vector_type(4))) float f32x4;
typedef __attribute__((ext_vector_type(16))) float f32x16;

__device__ __forceinline__ unsigned short f2bf(float f) {
  union { float f; unsigned int u; } v; v.f = f;
  unsigned int u = v.u + 0x7fffu + ((v.u >> 16) & 1u);
  return (unsigned short)(u >> 16);
}

__device__ __forceinline__ unsigned int cvtpk(float lo, float hi) {
  unsigned int r;
  asm("v_cvt_pk_bf16_f32 %0, %1, %2" : "=v"(r) : "v"(lo), "v"(hi));
  return r;
}

#define GLOAD16(gp, lp)                                                        \
  __builtin_amdgcn_global_load_lds(                                            \
      (const __attribute__((address_space(1))) unsigned int*)(gp),             \
      (__attribute__((address_space(3))) unsigned int*)(lp), 16, 0, 0)

// ---------- convert x fp32 -> bf16 ----------
__global__ __launch_bounds__(256) void cvt_x(const float* __restrict__ src,
                                             unsigned short* __restrict__ dst) {
  const size_t i = ((size_t)blockIdx.x * 256 + threadIdx.x) * 8;
  float4 a = *(const float4*)(src + i);
  float4 b = *(const float4*)(src + i + 4);
  bf16x8 w;
  w[0]=(short)f2bf(a.x); w[1]=(short)f2bf(a.y); w[2]=(short)f2bf(a.z); w[3]=(short)f2bf(a.w);
  w[4]=(short)f2bf(b.x); w[5]=(short)f2bf(b.y); w[6]=(short)f2bf(b.z); w[7]=(short)f2bf(b.w);
  *(bf16x8*)(dst + i) = w;
}

// ---------- transpose + convert: src[R][C] fp32 -> dst[C][R] bf16 ----------
__global__ __launch_bounds__(256) void tr_cvt(const float* __restrict__ src,
                                              unsigned short* __restrict__ dst,
                                              int R, int C) {
  __shared__ unsigned short t[32][34];
  const int tx = threadIdx.x & 31, ty = threadIdx.x >> 5;
  const int c0 = blockIdx.x * 32, r0 = blockIdx.y * 32;
#pragma unroll
  for (int i = 0; i < 4; ++i)
    t[ty + i * 8][tx] = f2bf(src[(size_t)(r0 + ty + i * 8) * C + c0 + tx]);
  __syncthreads();
#pragma unroll
  for (int i = 0; i < 4; ++i)
    dst[(size_t)(c0 + ty + i * 8) * R + r0 + tx] = t[tx][ty + i * 8];
}

// ---------- m97-style GEMM: A[M][1024] bf16, BT[N][1024] bf16 ----------
__global__ __launch_bounds__(256, 3) void gemm_qkv(
    const unsigned short* __restrict__ A, const unsigned short* __restrict__ BT,
    const float* __restrict__ Bias,
    unsigned short* __restrict__ Qo, unsigned short* __restrict__ Ko,
    unsigned short* __restrict__ Vo) {
  __shared__ __align__(16) unsigned short As[128][32];
  __shared__ __align__(16) unsigned short Bs[128][32];
  const int tid = threadIdx.x, lane = tid & 63, wv = tid >> 6;
  const int l15 = lane & 15, lg = lane >> 4;
  const int wrow = (wv >> 1) * 64, wcol = (wv & 1) * 64;
  const int cpx = gridDim.x >> 3;
  const int wg = (blockIdx.x & 7) * cpx + (blockIdx.x >> 3);
  const int mbase = (wg / 24) * 128, nbase = (wg % 24) * 128;

  f32x4 acc[4][4];
#pragma unroll
  for (int i = 0; i < 4; ++i)
#pragma unroll
    for (int j = 0; j < 4; ++j) acc[i][j] = (f32x4){0.f, 0.f, 0.f, 0.f};

  const int c0 = wv * 64 + lane;
  const unsigned short* ga0 = A + (size_t)(mbase + (c0 >> 2)) * EMB + (c0 & 3) * 8;
  const unsigned short* ga1 = ga0 + (size_t)64 * EMB;
  const unsigned short* gb0 = BT + (size_t)(nbase + (c0 >> 2)) * EMB + (c0 & 3) * 8;
  const unsigned short* gb1 = gb0 + (size_t)64 * EMB;
  unsigned short* la0 = &As[0][0] + c0 * 8;
  unsigned short* lb0 = &Bs[0][0] + c0 * 8;

  for (int k0 = 0; k0 < EMB; k0 += 32) {
    __syncthreads();
    GLOAD16(ga0 + k0, la0);
    GLOAD16(ga1 + k0, la0 + 2048);
    GLOAD16(gb0 + k0, lb0);
    GLOAD16(gb1 + k0, lb0 + 2048);
    __syncthreads();
    bf16x8 af[4], bfr[4];
#pragma unroll
    for (int mf = 0; mf < 4; ++mf)
      af[mf] = *(const bf16x8*)&As[wrow + mf * 16 + l15][lg * 8];
#pragma unroll
    for (int nf = 0; nf < 4; ++nf)
      bfr[nf] = *(const bf16x8*)&Bs[wcol + nf * 16 + l15][lg * 8];
#pragma unroll
    for (int mf = 0; mf < 4; ++mf)
#pragma unroll
      for (int nf = 0; nf < 4; ++nf)
        acc[mf][nf] = __builtin_amdgcn_mfma_f32_16x16x32_bf16(af[mf], bfr[nf], acc[mf][nf], 0, 0, 0);
  }

#pragma unroll
  for (int nf = 0; nf < 4; ++nf) {
    const int n = nbase + wcol + nf * 16 + l15;
    const float bias = Bias[n];
    const int which = n >> 10, rem = n & 1023;
    const int h = rem >> 6, d = rem & 63;
    unsigned short* dst = (which == 0) ? Qo : (which == 1) ? Ko : Vo;
#pragma unroll
    for (int mf = 0; mf < 4; ++mf)
#pragma unroll
      for (int j = 0; j < 4; ++j) {
        const int m = mbase + wrow + mf * 16 + lg * 4 + j;
        const int bb = m >> 11, s = m & 2047;
        dst[((size_t)(bb * NUMH + h) * SEQL + s) * HD + d] = f2bf(acc[mf][nf][j] + bias);
      }
  }
}

__global__ __launch_bounds__(256, 3) void gemm_out(
    const unsigned short* __restrict__ A, const unsigned short* __restrict__ BT,
    const float* __restrict__ Bias, float* __restrict__ Out) {
  __shared__ __align__(16) unsigned short As[128][32];
  __shared__ __align__(16) unsigned short Bs[128][32];
  const int tid = threadIdx.x, lane = tid & 63, wv = tid >> 6;
  const int l15 = lane & 15, lg = lane >> 4;
  const int wrow = (wv >> 1) * 64, wcol = (wv & 1) * 64;
  const int cpx = gridDim.x >> 3;
  const int wg = (blockIdx.x & 7) * cpx + (blockIdx.x >> 3);
  const int mbase = (wg >> 3) * 128, nbase = (wg & 7) * 128;

  f32x4 acc[4][4];
#pragma unroll
  for (int i = 0; i < 4; ++i)
#pragma unroll
    for (int j = 0; j < 4; ++j) acc[i][j] = (f32x4){0.f, 0.f, 0.f, 0.f};

  const int c0 = wv * 64 + lane;
  const unsigned short* ga0 = A + (size_t)(mbase + (c0 >> 2)) * EMB + (c0 & 3) * 8;
  const unsigned short* ga1 = ga0 + (size_t)64 * EMB;
  const unsigned short* gb0 = BT + (size_t)(nbase + (c0 >> 2)) * EMB + (c0 & 3) * 8;
  const unsigned short* gb1 = gb0 + (size_t)64 * EMB;
  unsigned short* la0 = &As[0][0] + c0 * 8;
  unsigned short* lb0 = &Bs[0][0] + c0 * 8;

  for (int k0 = 0; k0 < EMB; k0 += 32) {
    __syncthreads();
    GLOAD16(ga0 + k0, la0);
    GLOAD16(ga1 + k0, la0 + 2048);
    GLOAD16(gb0 + k0, lb0);
    GLOAD16(gb1 + k0, lb0 + 2048);
    __syncthreads();
    bf16x8 af[4], bfr[4];
#pragma unroll
    for (int mf = 0; mf < 4; ++mf)
      af[mf] = *(const bf16x8*)&As[wrow + mf * 16 + l15][lg * 8];
#pragma unroll
    for (int nf = 0; nf < 4; ++nf)
      bfr[nf] = *(const bf16x8*)&Bs[wcol + nf * 16 + l15][lg * 8];
#pragma unroll
    for (int mf = 0; mf < 4; ++mf)
#pragma unroll
      for (int nf = 0; nf < 4; ++nf)
        acc[mf][nf] = __builtin_amdgcn_mfma_f32_16x16x32_bf16(af[mf], bfr[nf], acc[mf][nf], 0, 0, 0);
  }

#pragma unroll
  for (int nf = 0; nf < 4; ++nf) {
    const int n = nbase + wcol + nf * 16 + l15;
    const float bias = Bias[n];
#pragma unroll
    for (int mf = 0; mf < 4; ++mf)
#pragma unroll
      for (int j = 0; j < 4; ++j) {
        const int m = mbase + wrow + mf * 16 + lg * 4 + j;
        Out[(size_t)m * EMB + n] = acc[mf][nf][j] + bias;
      }
  }
}

// ---------------- causal flash attention, swapped-operand (T12 style) -------
// 512 blocks, balanced pairs (qp, 15-qp). 4 waves x 32 q-rows. KVBLK=64.
// S^T = mfma(K, Q): lane owns q = lane&31; softmax lane-local.
// O^T = mfma(V^T, P^T): rescale is a lane scalar. P stays in registers.
// 32x32x16 C layout: col=lane&31, row=(reg&3)+8*(reg>>2)+4*(lane>>5).
__global__ __launch_bounds__(256, 3) void attn_fwd(
    const unsigned short* __restrict__ Q, const unsigned short* __restrict__ K,
    const unsigned short* __restrict__ V, unsigned short* __restrict__ O) {
  __shared__ __align__(16) unsigned short Ks[64][72];  // [kv][hd], pad 72 (16B stride)
  __shared__ __align__(16) unsigned short VT[64][72];  // [hd][kv]
  const int tid = threadIdx.x, lane = tid & 63, wv = tid >> 6;
  const int l31 = lane & 31, hi = lane >> 5;
  const int d0 = blockIdx.x;
  const int qp = (d0 >> 3) & 7;
  const int bh = ((d0 & 7) << 3) | (d0 >> 6);
  const int b = bh >> 4, h = bh & 15;
  const size_t bho = (size_t)(b * NUMH + h) * SEQL * HD;
  const unsigned short* Qb = Q + bho;
  const unsigned short* Kb = K + bho;
  const unsigned short* Vb = V + bho;
  const float AS = 0.18033688011112042f;  // 0.125 * log2(e)

  // staging assignments
  const int skrow = tid >> 2, skcol = (tid & 3) * 16;  // K: 64 rows x 4 chunks
  const int svrow = tid & 63, svd = (tid >> 6) * 16;   // V: 64 rows x 4 d-chunks

  for (int pass = 0; pass < 2; ++pass) {
    const int qt = pass ? (15 - qp) : qp;
    const int q0w = qt * 128 + wv * 32;
    const int qrow = q0w + l31;  // this lane's q row

    bf16x8 qf[4];
#pragma unroll
    for (int s = 0; s < 4; ++s)
      qf[s] = *(const bf16x8*)&Qb[(size_t)qrow * HD + s * 16 + hi * 8];

    f32x16 O0, O1;
#pragma unroll
    for (int i = 0; i < 16; ++i) { O0[i] = 0.f; O1[i] = 0.f; }
    float m_run = -1e30f, l_run = 0.f;

    const int nkt = 2 * qt + 2;
    for (int kt = 0; kt < nkt; ++kt) {
      const int ktb = kt * 64;
      __syncthreads();
      {  // stage K [64][64] -> Ks (padded rows)
        const unsigned short* kp = &Kb[(size_t)(ktb + skrow) * HD + skcol];
        uint4 k0 = *(const uint4*)kp;
        uint4 k1 = *(const uint4*)(kp + 8);
        *(uint4*)&Ks[skrow][skcol] = k0;
        *(uint4*)&Ks[skrow][skcol + 8] = k1;
      }
      {  // stage V transposed -> VT[d][kv]
        const unsigned short* vp = &Vb[(size_t)(ktb + svrow) * HD + svd];
        union { uint4 u[2]; unsigned short s[16]; } vb;
        vb.u[0] = *(const uint4*)vp;
        vb.u[1] = *(const uint4*)(vp + 8);
#pragma unroll
        for (int i = 0; i < 16; ++i) VT[svd + i][svrow] = vb.s[i];
      }
      __syncthreads();

      if (ktb <= q0w + 31) {  // wave-uniform participation
        // ---- S^T = K Q^T : D[kv][q], lane col = q ----
        f32x16 S0, S1;
#pragma unroll
        for (int i = 0; i < 16; ++i) { S0[i] = 0.f; S1[i] = 0.f; }
#pragma unroll
        for (int s = 0; s < 4; ++s) {
          bf16x8 kf0 = *(const bf16x8*)&Ks[l31][s * 16 + hi * 8];
          bf16x8 kf1 = *(const bf16x8*)&Ks[32 + l31][s * 16 + hi * 8];
          S0 = __builtin_amdgcn_mfma_f32_32x32x16_bf16(kf0, qf[s], S0, 0, 0, 0);
          S1 = __builtin_amdgcn_mfma_f32_32x32x16_bf16(kf1, qf[s], S1, 0, 0, 0);
        }
        // ---- causal mask (only near-diag tiles) ----
        if (ktb + 63 > q0w) {
#pragma unroll
          for (int r = 0; r < 16; ++r) {
            const int kv0 = ktb + (r & 3) + 8 * (r >> 2) + 4 * hi;
            S0[r] = (kv0 > qrow) ? -1e30f : S0[r];
            S1[r] = (kv0 + 32 > qrow) ? -1e30f : S1[r];
          }
        }
        // ---- lane-local softmax (raw units; 1/8 folded into exp2 scale) ----
        float t16[16];
#pragma unroll
        for (int i = 0; i < 16; ++i) t16[i] = fmaxf(S0[i], S1[i]);
#pragma unroll
        for (int i = 0; i < 8; ++i) t16[i] = fmaxf(t16[i], t16[i + 8]);
#pragma unroll
        for (int i = 0; i < 4; ++i) t16[i] = fmaxf(t16[i], t16[i + 4]);
        float mx = fmaxf(fmaxf(t16[0], t16[1]), fmaxf(t16[2], t16[3]));
        mx = fmaxf(mx, __shfl_xor(mx, 32));
        const float mn = fmaxf(m_run, mx);
        const float mk = mn * AS;
        const float sc = exp2f(__builtin_fmaf(m_run, AS, -mk));
        m_run = mn;
#pragma unroll
        for (int i = 0; i < 16; ++i) {
          S0[i] = exp2f(__builtin_fmaf(S0[i], AS, -mk));
          S1[i] = exp2f(__builtin_fmaf(S1[i], AS, -mk));
        }
        float a16[16];
#pragma unroll
        for (int i = 0; i < 16; ++i) a16[i] = S0[i] + S1[i];
#pragma unroll
        for (int i = 0; i < 8; ++i) a16[i] += a16[i + 8];
#pragma unroll
        for (int i = 0; i < 4; ++i) a16[i] += a16[i + 4];
        float rs = (a16[0] + a16[1]) + (a16[2] + a16[3]);
        rs += __shfl_xor(rs, 32);
        l_run = l_run * sc + rs;
#pragma unroll
        for (int i = 0; i < 16; ++i) { O0[i] *= sc; O1[i] *= sc; }

        // ---- P -> bf16 dwords; exchange halves; build B-frags P^T ----
        unsigned int W[2][4][2], X[2][4][2];
#pragma unroll
        for (int g = 0; g < 4; ++g)
#pragma unroll
          for (int c = 0; c < 2; ++c) {
            W[0][g][c] = cvtpk(S0[4 * g + 2 * c], S0[4 * g + 2 * c + 1]);
            W[1][g][c] = cvtpk(S1[4 * g + 2 * c], S1[4 * g + 2 * c + 1]);
          }
#pragma unroll
        for (int t = 0; t < 2; ++t)
#pragma unroll
          for (int g = 0; g < 4; ++g)
#pragma unroll
            for (int c = 0; c < 2; ++c) X[t][g][c] = __shfl_xor(W[t][g][c], 32);

        bf16x8 Pf[4];
#pragma unroll
        for (int ks = 0; ks < 4; ++ks) {
          const int t = ks >> 1, k1 = ks & 1;
          union { unsigned int d[4]; bf16x8 v; } u;
          u.d[0] = hi ? X[t][2 * k1 + 1][0] : W[t][2 * k1][0];
          u.d[1] = hi ? X[t][2 * k1 + 1][1] : W[t][2 * k1][1];
          u.d[2] = hi ? W[t][2 * k1 + 1][0] : X[t][2 * k1][0];
          u.d[3] = hi ? W[t][2 * k1 + 1][1] : X[t][2 * k1][1];
          Pf[ks] = u.v;
        }
        // ---- O^T += V^T P^T ----
#pragma unroll
        for (int ks = 0; ks < 4; ++ks) {
          bf16x8 vf0 = *(const bf16x8*)&VT[l31][ks * 16 + hi * 8];
          bf16x8 vf1 = *(const bf16x8*)&VT[32 + l31][ks * 16 + hi * 8];
          O0 = __builtin_amdgcn_mfma_f32_32x32x16_bf16(vf0, Pf[ks], O0, 0, 0, 0);
          O1 = __builtin_amdgcn_mfma_f32_32x32x16_bf16(vf1, Pf[ks], O1, 0, 0, 0);
        }
      }
    }
    // ---- epilogue: AO[b][q][h*64 + d], lane writes its q row ----
    const float inv = 1.0f / l_run;
    unsigned short* Op = O + ((size_t)b * SEQL + qrow) * EMB + h * HD;
#pragma unroll
    for (int g = 0; g < 4; ++g) {
      unsigned int w00 = cvtpk(O0[4 * g] * inv, O0[4 * g + 1] * inv);
      unsigned int w01 = cvtpk(O0[4 * g + 2] * inv, O0[4 * g + 3] * inv);
      unsigned int w10 = cvtpk(O1[4 * g] * inv, O1[4 * g + 1] * inv);
      unsigned int w11 = cvtpk(O1[4 * g + 2] * inv, O1[4 * g + 3] * inv);
      const int dd = 8 * g + 4 * hi;
      *(uint2*)&Op[dd]      = uint2{w00, w01};
      *(uint2*)&Op[32 + dd] = uint2{w10, w11};
    }
  }
}

extern "C" void kernel_launch(void* const* d_in, const int* in_sizes, int n_in,
                              void* d_out, int out_size, void* d_ws, size_t ws_size,
                              hipStream_t stream) {
  const float* x     = (const float*)d_in[0];
  const float* w_qkv = (const float*)d_in[1];
  const float* b_qkv = (const float*)d_in[2];
  const float* w_out = (const float*)d_in[3];
  const float* b_out = (const float*)d_in[4];
  float* out = (float*)d_out;

  const size_t NE = (size_t)BATCH * NUMH * SEQL * HD;  // 8,388,608
  unsigned short* Qb = (unsigned short*)d_ws;
  unsigned short* Kb = Qb + NE;
  unsigned short* Vb = Kb + NE;
  unsigned short* AO = Vb + NE;
  unsigned short* xb = AO + NE;
  unsigned short* wqkvT = xb + NE;              // [3072][1024]
  unsigned short* woutT = wqkvT + 3072 * 1024;  // [1024][1024]

  cvt_x<<<dim3((unsigned)(NE / (256 * 8))), 256, 0, stream>>>(x, xb);
  tr_cvt<<<dim3(3072 / 32, 1024 / 32), 256, 0, stream>>>(w_qkv, wqkvT, 1024, 3072);
  tr_cvt<<<dim3(1024 / 32, 1024 / 32), 256, 0, stream>>>(w_out, woutT, 1024, 1024);

  gemm_qkv<<<dim3(1536), 256, 0, stream>>>(xb, wqkvT, b_qkv, Qb, Kb, Vb);
  attn_fwd<<<dim3(512), 256, 0, stream>>>(Qb, Kb, Vb, AO);
  gemm_out<<<dim3(512), 256, 0, stream>>>(AO, woutT, b_out, out);
}